// Round 1
// baseline (431.828 us; speedup 1.0000x reference)
//
#include <hip/hip_runtime.h>
#include <hip/hip_bf16.h>
#include <stdint.h>

// ArcFace: out[n][c] = 64 * margin(cos[n][c]),  cos = norm_rows(x) @ norm_rows(W)^T
// N=512, D=512, C=100000.
// Pipeline: (1) normalize x -> bf16, (2) normalize W -> bf16 (padded to 100096 rows),
// (3) bf16 MFMA GEMM with clip+scale epilogue, (4) 512-thread label fixup.

#define NROWS 512
#define DDIM 512
#define NCLS 100000
#define NCLS_PAD 100096   // 782 * 128

typedef __attribute__((ext_vector_type(8))) short bf16x8;
typedef __attribute__((ext_vector_type(4))) float f32x4;

__device__ __forceinline__ unsigned short f2bf(float x) {
    union { float f; uint32_t u; } c; c.f = x;
    uint32_t u = c.u;
    uint32_t r = (u + 0x7FFFu + ((u >> 16) & 1u)) >> 16;
    return (unsigned short)r;
}

__device__ __forceinline__ void g2lds16(const void* g, void* l) {
    __builtin_amdgcn_global_load_lds(
        (const __attribute__((address_space(1))) void*)g,
        (__attribute__((address_space(3))) void*)l,
        16, 0, 0);
}

// One wave per row: load 512 f32, sum-of-squares reduce, rsqrt, store 512 bf16.
// Rows in [validRows, totalRows) are written as zeros (padding for GEMM tiles).
__global__ __launch_bounds__(256)
void rownorm_bf16(const float* __restrict__ in, unsigned short* __restrict__ out,
                  int validRows, int totalRows) {
    const int row  = blockIdx.x * 4 + (threadIdx.x >> 6);
    const int lane = threadIdx.x & 63;
    if (row >= totalRows) return;

    unsigned short* orow = out + (size_t)row * DDIM;
    if (row >= validRows) {
        ushort4 z = {0, 0, 0, 0};
        *(ushort4*)(orow + lane * 4) = z;
        *(ushort4*)(orow + 256 + lane * 4) = z;
        return;
    }

    const float4* p = (const float4*)(in + (size_t)row * DDIM);
    float4 v0 = p[lane];        // elements 4*lane .. +3
    float4 v1 = p[64 + lane];   // elements 256+4*lane .. +3

    float ss = v0.x*v0.x + v0.y*v0.y + v0.z*v0.z + v0.w*v0.w
             + v1.x*v1.x + v1.y*v1.y + v1.z*v1.z + v1.w*v1.w;
    #pragma unroll
    for (int off = 32; off > 0; off >>= 1) ss += __shfl_xor(ss, off);
    const float r = rsqrtf(ss);

    ushort4 o0, o1;
    o0.x = f2bf(v0.x * r); o0.y = f2bf(v0.y * r);
    o0.z = f2bf(v0.z * r); o0.w = f2bf(v0.w * r);
    o1.x = f2bf(v1.x * r); o1.y = f2bf(v1.y * r);
    o1.z = f2bf(v1.z * r); o1.w = f2bf(v1.w * r);
    *(ushort4*)(orow + lane * 4) = o0;
    *(ushort4*)(orow + 256 + lane * 4) = o1;
}

// 128x128 tile bf16 MFMA GEMM (m97 structure): 256 threads = 4 waves (2x2),
// each wave owns a 64x64 sub-tile = 4x4 fragments of 16x16x32.
// A: [512][512] bf16 row-major (normalized x). B: [100096][512] bf16 row-major
// (normalized W; B^T-layout GEMM, K contiguous in both operands).
__global__ __launch_bounds__(256)
void arcface_gemm(const unsigned short* __restrict__ A,
                  const unsigned short* __restrict__ B,
                  float* __restrict__ out) {
    __shared__ unsigned short As[128 * 32];
    __shared__ unsigned short Bs[128 * 32];

    const int t    = threadIdx.x;
    const int lane = t & 63;
    const int wid  = t >> 6;
    const int wr   = wid >> 1;          // wave row 0..1
    const int wc   = wid & 1;           // wave col 0..1
    const int rowBase = blockIdx.y * 128;
    const int colBase = blockIdx.x * 128;

    f32x4 acc[4][4] = {};

    // staging geometry: thread t fetches 16B = 8 bf16; row r0 = t/4, col (t%4)*8
    const int r0 = t >> 2;              // 0..63
    const int c0 = (t & 3) << 3;        // 0,8,16,24
    const unsigned short* gA = A + (size_t)(rowBase + r0) * DDIM + c0;
    const unsigned short* gB = B + (size_t)(colBase + r0) * DDIM + c0;

    const int kg = (lane >> 4) << 3;    // k-group offset 0,8,16,24
    const int fr = lane & 15;           // fragment row/col within 16

    for (int kt = 0; kt < DDIM; kt += 32) {
        __syncthreads();   // previous tile's reads done before overwrite
        g2lds16(gA + kt,                 &As[t * 8]);
        g2lds16(gA + kt + 64 * DDIM,     &As[2048 + t * 8]);
        g2lds16(gB + kt,                 &Bs[t * 8]);
        g2lds16(gB + kt + 64 * DDIM,     &Bs[2048 + t * 8]);
        __syncthreads();   // drains vmcnt before barrier -> tiles ready

        bf16x8 a[4], b[4];
        #pragma unroll
        for (int m = 0; m < 4; ++m)
            a[m] = *(const bf16x8*)&As[(wr * 64 + m * 16 + fr) * 32 + kg];
        #pragma unroll
        for (int n = 0; n < 4; ++n)
            b[n] = *(const bf16x8*)&Bs[(wc * 64 + n * 16 + fr) * 32 + kg];

        #pragma unroll
        for (int m = 0; m < 4; ++m)
            #pragma unroll
            for (int n = 0; n < 4; ++n)
                acc[m][n] = __builtin_amdgcn_mfma_f32_16x16x32_bf16(
                    a[m], b[n], acc[m][n], 0, 0, 0);
    }

    // epilogue: clip to [-1+1e-7, 1-1e-7], scale by 64.
    // C/D layout (m89-verified): col = lane&15, row = (lane>>4)*4 + i
    const float lo = -1.0f + 1e-7f, hi = 1.0f - 1e-7f;
    #pragma unroll
    for (int m = 0; m < 4; ++m) {
        const int r = rowBase + wr * 64 + m * 16 + (lane >> 4) * 4;
        #pragma unroll
        for (int n = 0; n < 4; ++n) {
            const int c = colBase + wc * 64 + n * 16 + fr;
            if (c < NCLS) {
                #pragma unroll
                for (int i = 0; i < 4; ++i) {
                    float v = acc[m][n][i];
                    v = fminf(fmaxf(v, lo), hi);
                    out[(size_t)(r + i) * NCLS + c] = 64.0f * v;
                }
            }
        }
    }
}

// Label-column margin fixup. t = clipped cos (recovered exactly: /64 is a pow2 scale).
// cond uses unclipped cos in the reference, but clip only changes values beyond
// +/-(1-1e-7) and both sides of THRESH=-0.8776 compare identically after clip.
__global__ void arcface_fixup(const int* __restrict__ label, float* __restrict__ out) {
    const int n = blockIdx.x * 64 + threadIdx.x;
    if (n >= NROWS) return;
    const int c = label[n];
    const size_t idx = (size_t)n * NCLS + c;
    const float t = out[idx] * 0.015625f;   // /64
    const float COSM = 0.8775825618903728f;  // cos(0.5)
    const float SINM = 0.479425538604203f;   // sin(0.5)
    const float MM   = 0.2397127693021015f;  // sin(0.5)*0.5
    const float THRESH = -0.8775825618903728f; // cos(pi-0.5)
    float r;
    if (t > THRESH) {
        r = t * COSM - sqrtf(fmaxf(1.0f - t * t, 0.0f)) * SINM;
    } else {
        r = t - MM;
    }
    out[idx] = 64.0f * r;
}

extern "C" void kernel_launch(void* const* d_in, const int* in_sizes, int n_in,
                              void* d_out, int out_size, void* d_ws, size_t ws_size,
                              hipStream_t stream) {
    const float* x     = (const float*)d_in[0];
    const int*   label = (const int*)d_in[1];
    const float* w     = (const float*)d_in[2];
    float* out = (float*)d_out;

    unsigned short* Abf = (unsigned short*)d_ws;                       // 512*512 bf16
    unsigned short* Wbf = (unsigned short*)d_ws + (size_t)NROWS * DDIM; // 100096*512 bf16

    // normalize x: 512 rows, 4 rows/block
    rownorm_bf16<<<NROWS / 4, 256, 0, stream>>>(x, Abf, NROWS, NROWS);
    // normalize W: 100096 rows (96 zero-pad rows)
    rownorm_bf16<<<NCLS_PAD / 4, 256, 0, stream>>>(w, Wbf, NCLS, NCLS_PAD);

    dim3 grid(NCLS_PAD / 128, NROWS / 128);   // 782 x 4
    arcface_gemm<<<grid, 256, 0, stream>>>(Abf, Wbf, out);

    arcface_fixup<<<(NROWS + 63) / 64, 64, 0, stream>>>(label, out);
}

// Round 2
// 423.810 us; speedup vs baseline: 1.0189x; 1.0189x over previous
//
#include <hip/hip_runtime.h>
#include <hip/hip_bf16.h>
#include <stdint.h>

// ArcFace fused: out[n][c] = 64 * margin(clip( (x_hat . w_c) / ||w_c|| ))
// N=512, D=512, C=100000.
// Pipeline: (1) normalize x -> bf16 (tiny), (2) fused GEMM: reads raw f32 W,
// converts to bf16 during reg-staging, accumulates per-class sum-of-squares in
// the K loop, applies rsqrt(ss) + clip + scale in the epilogue,
// (3) 512-thread label margin fixup.

#define NROWS 512
#define DDIM 512
#define NCLS 100000

typedef __attribute__((ext_vector_type(8))) short bf16x8;
typedef __attribute__((ext_vector_type(8))) unsigned short u16x8;
typedef __attribute__((ext_vector_type(4))) float f32x4;

__device__ __forceinline__ unsigned short f2bf(float x) {
    union { float f; uint32_t u; } c; c.f = x;
    uint32_t r = (c.u + 0x7FFFu + ((c.u >> 16) & 1u)) >> 16;
    return (unsigned short)r;
}

__device__ __forceinline__ void g2lds16(const void* g, void* l) {
    __builtin_amdgcn_global_load_lds(
        (const __attribute__((address_space(1))) void*)g,
        (__attribute__((address_space(3))) void*)l, 16, 0, 0);
}

// One wave per row: normalize x rows to unit L2 norm, store bf16.
__global__ __launch_bounds__(256)
void rownorm_x(const float* __restrict__ in, unsigned short* __restrict__ out) {
    const int row  = blockIdx.x * 4 + (threadIdx.x >> 6);
    const int lane = threadIdx.x & 63;

    const float4* p = (const float4*)(in + (size_t)row * DDIM);
    float4 v0 = p[lane];
    float4 v1 = p[64 + lane];

    float ss = v0.x*v0.x + v0.y*v0.y + v0.z*v0.z + v0.w*v0.w
             + v1.x*v1.x + v1.y*v1.y + v1.z*v1.z + v1.w*v1.w;
    #pragma unroll
    for (int off = 32; off > 0; off >>= 1) ss += __shfl_xor(ss, off);
    const float r = rsqrtf(ss);

    unsigned short* orow = out + (size_t)row * DDIM;
    ushort4 o0, o1;
    o0.x = f2bf(v0.x * r); o0.y = f2bf(v0.y * r);
    o0.z = f2bf(v0.z * r); o0.w = f2bf(v0.w * r);
    o1.x = f2bf(v1.x * r); o1.y = f2bf(v1.y * r);
    o1.z = f2bf(v1.z * r); o1.w = f2bf(v1.w * r);
    *(ushort4*)(orow + lane * 4) = o0;
    *(ushort4*)(orow + 256 + lane * 4) = o1;
}

// Fused 128x128 bf16 MFMA GEMM over raw f32 W.
// 256 threads = 4 waves (2x2), each wave a 64x64 sub-tile (4x4 frags of 16x16x32).
// A: [512][512] bf16 normalized (gload_lds staging, linear LDS).
// B: f32 W rows staged via regs: load float4 x4 -> convert bf16 -> ds_write,
//    LDS row stride padded to 40 shorts (80 B) to break ds_write/read conflicts.
// B-prefetch for kt+32 issued after the second barrier (hides HBM latency
// under the MFMA phase; T14 async-split).
__global__ __launch_bounds__(256)
void arcface_gemm_fused(const unsigned short* __restrict__ A,
                        const float* __restrict__ W,
                        float* __restrict__ out) {
    __shared__ unsigned short As[128 * 32];   // 8 KB, linear (gload_lds dest)
    __shared__ unsigned short Bs[128 * 40];   // 10 KB, padded stride
    __shared__ float sm[256];                 // per-(class-row, half) ss partials

    const int t    = threadIdx.x;
    const int lane = t & 63;
    const int wid  = t >> 6;
    const int wr   = wid >> 1;
    const int wc   = wid & 1;
    const int rowBase = blockIdx.x * 128;     // 4 row tiles (x fastest: blocks
    const int colBase = blockIdx.y * 128;     // sharing a W panel run adjacent)

    f32x4 acc[4][4] = {};

    // A staging: thread t fetches 16B; rows t>>2 and t>>2 + 64
    const unsigned short* gA = A + (size_t)(rowBase + (t >> 2)) * DDIM + ((t & 3) << 3);

    // B staging: thread t -> class row r0 = t>>1, col-half cs = (t&1)*16
    const int r0 = t >> 1;
    const int cs = (t & 1) << 4;
    const int bRow = colBase + r0;
    const bool bValid = bRow < NCLS;
    const float* gB = W + (size_t)bRow * DDIM + cs;
    unsigned short* wB = &Bs[r0 * 40 + cs];

    const int kg = (lane >> 4) << 3;          // k-group offset 0,8,16,24
    const int fr = lane & 15;

    float ss = 0.0f;
    float4 pf0, pf1, pf2, pf3;
    if (bValid) {
        pf0 = *(const float4*)(gB + 0);
        pf1 = *(const float4*)(gB + 4);
        pf2 = *(const float4*)(gB + 8);
        pf3 = *(const float4*)(gB + 12);
    } else {
        pf0 = float4{0.f,0.f,0.f,0.f}; pf1 = pf0; pf2 = pf0; pf3 = pf0;
    }

    for (int kt = 0; kt < DDIM; kt += 32) {
        __syncthreads();   // previous tile's LDS reads done before overwrite
        g2lds16(gA + kt,             &As[t * 8]);
        g2lds16(gA + kt + 64 * DDIM, &As[2048 + t * 8]);

        // convert prefetched f32 -> bf16, accumulate sum of squares, write LDS
        ss += pf0.x*pf0.x + pf0.y*pf0.y + pf0.z*pf0.z + pf0.w*pf0.w;
        ss += pf1.x*pf1.x + pf1.y*pf1.y + pf1.z*pf1.z + pf1.w*pf1.w;
        ss += pf2.x*pf2.x + pf2.y*pf2.y + pf2.z*pf2.z + pf2.w*pf2.w;
        ss += pf3.x*pf3.x + pf3.y*pf3.y + pf3.z*pf3.z + pf3.w*pf3.w;
        u16x8 w0, w1;
        w0[0] = f2bf(pf0.x); w0[1] = f2bf(pf0.y); w0[2] = f2bf(pf0.z); w0[3] = f2bf(pf0.w);
        w0[4] = f2bf(pf1.x); w0[5] = f2bf(pf1.y); w0[6] = f2bf(pf1.z); w0[7] = f2bf(pf1.w);
        w1[0] = f2bf(pf2.x); w1[1] = f2bf(pf2.y); w1[2] = f2bf(pf2.z); w1[3] = f2bf(pf2.w);
        w1[4] = f2bf(pf3.x); w1[5] = f2bf(pf3.y); w1[6] = f2bf(pf3.z); w1[7] = f2bf(pf3.w);
        *(u16x8*)(wB)     = w0;   // ds_write_b128
        *(u16x8*)(wB + 8) = w1;   // ds_write_b128

        __syncthreads();   // A vmcnt drained + B writes visible

        // async prefetch of next B chunk: latency hides under MFMA phase
        if (kt + 32 < DDIM && bValid) {
            const float* g = gB + kt + 32;
            pf0 = *(const float4*)(g + 0);
            pf1 = *(const float4*)(g + 4);
            pf2 = *(const float4*)(g + 8);
            pf3 = *(const float4*)(g + 12);
        }

        bf16x8 a[4], b[4];
        #pragma unroll
        for (int m = 0; m < 4; ++m)
            a[m] = *(const bf16x8*)&As[(wr * 64 + m * 16 + fr) * 32 + kg];
        #pragma unroll
        for (int n = 0; n < 4; ++n)
            b[n] = *(const bf16x8*)&Bs[(wc * 64 + n * 16 + fr) * 40 + kg];

        #pragma unroll
        for (int m = 0; m < 4; ++m)
            #pragma unroll
            for (int n = 0; n < 4; ++n)
                acc[m][n] = __builtin_amdgcn_mfma_f32_16x16x32_bf16(
                    a[m], b[n], acc[m][n], 0, 0, 0);
    }

    // reduce per-class sum of squares: sm[t] == sm[r0*2 + half]
    sm[t] = ss;
    __syncthreads();

    const float lo = -1.0f + 1e-7f, hi = 1.0f - 1e-7f;
    float rn[4];
    #pragma unroll
    for (int n = 0; n < 4; ++n) {
        const int cl = wc * 64 + n * 16 + fr;
        rn[n] = rsqrtf(sm[cl * 2] + sm[cl * 2 + 1]);
    }

    // C/D layout: col = lane&15, row = (lane>>4)*4 + i
    #pragma unroll
    for (int m = 0; m < 4; ++m) {
        const int r = rowBase + wr * 64 + m * 16 + (lane >> 4) * 4;
        #pragma unroll
        for (int n = 0; n < 4; ++n) {
            const int c = colBase + wc * 64 + n * 16 + fr;
            if (c < NCLS) {
                #pragma unroll
                for (int i = 0; i < 4; ++i) {
                    float v = acc[m][n][i] * rn[n];
                    v = fminf(fmaxf(v, lo), hi);
                    out[(size_t)(r + i) * NCLS + c] = 64.0f * v;
                }
            }
        }
    }
}

// Label-column margin fixup (t recovered exactly: /64 is a pow2 scale).
__global__ void arcface_fixup(const int* __restrict__ label, float* __restrict__ out) {
    const int n = blockIdx.x * 64 + threadIdx.x;
    if (n >= NROWS) return;
    const int c = label[n];
    const size_t idx = (size_t)n * NCLS + c;
    const float t = out[idx] * 0.015625f;    // /64
    const float COSM = 0.8775825618903728f;  // cos(0.5)
    const float SINM = 0.479425538604203f;   // sin(0.5)
    const float MM   = 0.2397127693021015f;  // sin(0.5)*0.5
    const float THRESH = -0.8775825618903728f; // cos(pi-0.5)
    float r;
    if (t > THRESH) {
        r = t * COSM - sqrtf(fmaxf(1.0f - t * t, 0.0f)) * SINM;
    } else {
        r = t - MM;
    }
    out[idx] = 64.0f * r;
}

extern "C" void kernel_launch(void* const* d_in, const int* in_sizes, int n_in,
                              void* d_out, int out_size, void* d_ws, size_t ws_size,
                              hipStream_t stream) {
    const float* x     = (const float*)d_in[0];
    const int*   label = (const int*)d_in[1];
    const float* w     = (const float*)d_in[2];
    float* out = (float*)d_out;

    unsigned short* Abf = (unsigned short*)d_ws;   // 512*512 bf16

    rownorm_x<<<NROWS / 4, 256, 0, stream>>>(x, Abf);

    // grid.x = 4 row-tiles (fastest-varying: blocks sharing a W panel are
    // dispatched adjacently -> W read from HBM ~once), grid.y = 782 col-tiles
    dim3 grid(NROWS / 128, (NCLS + 127) / 128);
    arcface_gemm_fused<<<grid, 256, 0, stream>>>(Abf, w, out);

    arcface_fixup<<<(NROWS + 63) / 64, 64, 0, stream>>>(label, out);
}